// Round 7
// baseline (88.936 us; speedup 1.0000x reference)
//
#include <hip/hip_runtime.h>

#define NB 8192
#define NT 64
#define FCAP 5.0f

typedef unsigned int u32;
typedef float f32x4 __attribute__((ext_vector_type(4)));
typedef __bf16 bf16x8 __attribute__((ext_vector_type(8)));
typedef u32 u32x4 __attribute__((ext_vector_type(4)));
typedef u32 u32x2 __attribute__((ext_vector_type(2)));

static __device__ __forceinline__ u32 pk2(float lo, float hi) {
  u32 r;
  asm("v_cvt_pk_bf16_f32 %0, %1, %2" : "=v"(r) : "v"(lo), "v"(hi));
  return r;
}
static __device__ __forceinline__ float clipc(float a) { return fminf(fmaxf(a, -FCAP), FCAP); }

// pack 8 consecutive f32 into one bf16x8 fragment (RNE)
static __device__ __forceinline__ bf16x8 mkfrag(const float* __restrict__ p) {
  f32x4 a = *(const f32x4*)p, b = *(const f32x4*)(p + 4);
  u32x4 wv = {pk2(a[0], a[1]), pk2(a[2], a[3]), pk2(b[0], b[1]), pk2(b[2], b[3])};
  return __builtin_bit_cast(bf16x8, wv);
}

#define MFMA16(A, B, C) __builtin_amdgcn_mfma_f32_16x16x32_bf16(A, B, C, 0, 0, 0)

// leaky_relu on 4 packed f32 (v_pk_mul_f32 + v_pk_max_f32)
static __device__ __forceinline__ f32x4 lrelu4(f32x4 v) {
  return __builtin_elementwise_max(v, v * 0.01f);
}

// 16x16x32 bf16 layouts (HW-verified rounds 3/5):
//   A: row = lane&15, k = 32*kt + 8*(lane>>4) + e
//   B: col = lane&15, k = 32*kt + 8*(lane>>4) + e
//   C: col = lane&15, row = 4*(lane>>4) + reg
//
// Per-step dataflow (this round): L1 fully per-lane VALU (each lane builds its
// own 32 h1 values = its B-frag k-set, from f32 W1/b1 in VGPRs) -> L2 MFMA
// (local B) -> h2 via LDS broadcast (barrier 1) -> L3 MFMA -> h3 stays in C
// regs -> L4 = per-lane f32 dot + shfl_xor(16/32) reduce -> fbuf exchange
// (barrier 2) -> Euler. 2 barriers/step, ~9 LDS ops/wave.
__global__ __launch_bounds__(256, 2) void ode_kernel(
    const float* __restrict__ ts, const float* __restrict__ y0,
    const float* __restrict__ W1, const float* __restrict__ b1,
    const float* __restrict__ W2, const float* __restrict__ b2,
    const float* __restrict__ W3, const float* __restrict__ b3,
    const float* __restrict__ W4, const float* __restrict__ b4,
    float* __restrict__ out) {
  const int tid = threadIdx.x;
  const int wv = __builtin_amdgcn_readfirstlane(tid >> 6);  // wave 0..3
  const int l = tid & 63;
  const int g = l >> 4;   // lane group 0..3
  const int c = l & 15;   // particle col
  const int gp0 = blockIdx.x * 16;

  __shared__ alignas(16) u32 bufA[16 * 68];   // h2 broadcast, stride 68 words
  __shared__ alignas(16) float fbuf[16 * 20]; // [c][wv][2] @ stride 20

  // ---- W2/W3 A-fragments (2 M-tiles x 4 k-tiles, bf16 RNE) ----
  bf16x8 aW2[2][4], aW3[2][4];
#pragma unroll
  for (int mt = 0; mt < 2; ++mt) {
    const int R = 32 * wv + 16 * mt + c;
#pragma unroll
    for (int kt = 0; kt < 4; ++kt) {
      aW2[mt][kt] = mkfrag(W2 + R * 128 + 32 * kt + 8 * g);
      aW3[mt][kt] = mkfrag(W3 + R * 128 + 32 * kt + 8 * g);
    }
  }
  // ---- W1/b1 per-lane f32 (rows k = 32kt + 8g + e, this lane's B k-set) ----
  float w1a[4][8], w1b[4][8], bb1[4][8];
#pragma unroll
  for (int kt = 0; kt < 4; ++kt) {
#pragma unroll
    for (int e = 0; e < 8; ++e) {
      const int r = 32 * kt + 8 * g + e;
      w1a[kt][e] = W1[2 * r];
      w1b[kt][e] = W1[2 * r + 1];
      bb1[kt][e] = b1[r];
    }
  }
  // ---- W4 per-lane f32 (this lane's 8 own h3 rows) ----
  float w40[8], w41[8];
#pragma unroll
  for (int mt = 0; mt < 2; ++mt) {
#pragma unroll
    for (int rr = 0; rr < 4; ++rr) {
      const int row = 32 * wv + 16 * mt + 4 * g + rr;
      w40[mt * 4 + rr] = W4[row];
      w41[mt * 4 + rr] = W4[128 + row];
    }
  }
  // ---- b2/b3 C-inits: C row = 32wv + 16mt + 4g + r ----
  f32x4 cb2[2], cb3[2];
#pragma unroll
  for (int mt = 0; mt < 2; ++mt) {
#pragma unroll
    for (int r = 0; r < 4; ++r) {
      const int row = 32 * wv + 16 * mt + 4 * g + r;
      cb2[mt][r] = b2[row];
      cb3[mt][r] = b3[row];
    }
  }
  const float b40 = b4[0], b41 = b4[1];

  // ---- state: all lanes track y for col c ----
  float y1 = y0[(gp0 + c) * 2];
  float y2 = y0[(gp0 + c) * 2 + 1];

  if (wv == 0 && g == 0) {
    float2 st = {clipc(y1), clipc(y2)};
    *(float2*)(out + (gp0 + c) * 2) = st;
  }

  const f32x4 zero4 = {0.f, 0.f, 0.f, 0.f};
  const int wbase = 68 * c + 16 * wv + 2 * g;  // h2 write base (M-tile 0)
  const int rbase = 68 * c + 4 * g;            // h2 read base (k-tile 0)

#pragma unroll 1
  for (int t = 0; t < NT - 1; ++t) {
    const float dt = ts[t + 1] - ts[t];

    // ---- layer 1: per-lane VALU, full h1 B-frags locally (no LDS) ----
    u32x4 hb[4];
#pragma unroll
    for (int kt = 0; kt < 4; ++kt) {
      float hv[8];
#pragma unroll
      for (int e = 0; e < 8; ++e) {
        const float a = fmaf(w1a[kt][e], y1, fmaf(w1b[kt][e], y2, bb1[kt][e]));
        hv[e] = fmaxf(a, 0.01f * a);
      }
      hb[kt] = (u32x4){pk2(hv[0], hv[1]), pk2(hv[2], hv[3]),
                       pk2(hv[4], hv[5]), pk2(hv[6], hv[7])};
    }

    // ---- layer 2: 8 MFMA from local B-frags ----
    f32x4 C0, C1;
    {
      const bf16x8 q0 = __builtin_bit_cast(bf16x8, hb[0]);
      const bf16x8 q1 = __builtin_bit_cast(bf16x8, hb[1]);
      const bf16x8 q2 = __builtin_bit_cast(bf16x8, hb[2]);
      const bf16x8 q3 = __builtin_bit_cast(bf16x8, hb[3]);
      f32x4 D0 = MFMA16(aW2[0][0], q0, cb2[0]);
      f32x4 D1 = MFMA16(aW2[1][0], q0, cb2[1]);
      f32x4 E0 = MFMA16(aW2[0][1], q1, zero4);
      f32x4 E1 = MFMA16(aW2[1][1], q1, zero4);
      D0 = MFMA16(aW2[0][2], q2, D0);
      D1 = MFMA16(aW2[1][2], q2, D1);
      E0 = MFMA16(aW2[0][3], q3, E0);
      E1 = MFMA16(aW2[1][3], q3, E1);
      C0 = lrelu4(D0 + E0);
      C1 = lrelu4(D1 + E1);
    }
    *(__shared__ u32x2*)&bufA[wbase]     = (u32x2){pk2(C0[0], C0[1]), pk2(C0[2], C0[3])};
    *(__shared__ u32x2*)&bufA[wbase + 8] = (u32x2){pk2(C1[0], C1[1]), pk2(C1[2], C1[3])};
    __syncthreads();  // barrier 1: h2 broadcast

    // ---- layer 3: 8 MFMA; h3 stays in registers ----
    f32x4 H0, H1;
    {
      const bf16x8 q0 = __builtin_bit_cast(bf16x8, *(const __shared__ u32x4*)&bufA[rbase]);
      const bf16x8 q1 = __builtin_bit_cast(bf16x8, *(const __shared__ u32x4*)&bufA[rbase + 16]);
      const bf16x8 q2 = __builtin_bit_cast(bf16x8, *(const __shared__ u32x4*)&bufA[rbase + 32]);
      const bf16x8 q3 = __builtin_bit_cast(bf16x8, *(const __shared__ u32x4*)&bufA[rbase + 48]);
      f32x4 D0 = MFMA16(aW3[0][0], q0, cb3[0]);
      f32x4 D1 = MFMA16(aW3[1][0], q0, cb3[1]);
      f32x4 E0 = MFMA16(aW3[0][1], q1, zero4);
      f32x4 E1 = MFMA16(aW3[1][1], q1, zero4);
      D0 = MFMA16(aW3[0][2], q2, D0);
      D1 = MFMA16(aW3[1][2], q2, D1);
      E0 = MFMA16(aW3[0][3], q3, E0);
      E1 = MFMA16(aW3[1][3], q3, E1);
      H0 = lrelu4(D0 + E0);
      H1 = lrelu4(D1 + E1);
    }

    // ---- layer 4: per-lane f32 dot over own 8 h3 rows + cross-lane reduce ----
    float f0 = 0.f, f1 = 0.f;
#pragma unroll
    for (int rr = 0; rr < 4; ++rr) {
      f0 = fmaf(w40[rr], H0[rr], f0);
      f0 = fmaf(w40[4 + rr], H1[rr], f0);
      f1 = fmaf(w41[rr], H0[rr], f1);
      f1 = fmaf(w41[4 + rr], H1[rr], f1);
    }
    f0 += __shfl_xor(f0, 16);
    f1 += __shfl_xor(f1, 16);
    f0 += __shfl_xor(f0, 32);
    f1 += __shfl_xor(f1, 32);
    if (g == 0)
      *(__shared__ float2*)&fbuf[c * 20 + wv * 2] = (float2){f0, f1};
    __syncthreads();  // barrier 2: wave partials

    // ---- reduce 4 wave-partials + Euler update (uniform across lanes) ----
    const f32x4 pa = *(const __shared__ f32x4*)&fbuf[c * 20];
    const f32x4 pb = *(const __shared__ f32x4*)&fbuf[c * 20 + 4];
    const f32x4 s = pa + pb;
    const float ft0 = b40 + s[0] + s[2];
    const float ft1 = b41 + s[1] + s[3];
    y1 += dt * (ft0 - y1);
    y2 += dt * (ft1 - y2);

    if (wv == 0 && g == 0) {
      float2 st = {clipc(y1), clipc(y2)};
      *(float2*)(out + (t + 1) * (NB * 2) + (gp0 + c) * 2) = st;
    }
  }
}

extern "C" void kernel_launch(void* const* d_in, const int* in_sizes, int n_in,
                              void* d_out, int out_size, void* d_ws, size_t ws_size,
                              hipStream_t stream) {
  const float* ts = (const float*)d_in[0];
  const float* y0 = (const float*)d_in[1];
  const float* W1 = (const float*)d_in[2];
  const float* b1 = (const float*)d_in[3];
  const float* W2 = (const float*)d_in[4];
  const float* b2 = (const float*)d_in[5];
  const float* W3 = (const float*)d_in[6];
  const float* b3 = (const float*)d_in[7];
  const float* W4 = (const float*)d_in[8];
  const float* b4 = (const float*)d_in[9];

  ode_kernel<<<NB / 16, 256, 0, stream>>>(ts, y0, W1, b1, W2, b2, W3, b3, W4, b4,
                                          (float*)d_out);
}

// Round 8
// 70.668 us; speedup vs baseline: 1.2585x; 1.2585x over previous
//
#include <hip/hip_runtime.h>

#define NB 8192
#define NT 64
#define FCAP 5.0f

typedef unsigned int u32;
typedef float f32x4 __attribute__((ext_vector_type(4)));
typedef __bf16 bf16x8 __attribute__((ext_vector_type(8)));
typedef u32 u32x4 __attribute__((ext_vector_type(4)));
typedef u32 u32x2 __attribute__((ext_vector_type(2)));

static __device__ __forceinline__ u32 pk2(float lo, float hi) {
  u32 r;
  asm("v_cvt_pk_bf16_f32 %0, %1, %2" : "=v"(r) : "v"(lo), "v"(hi));
  return r;
}
static __device__ __forceinline__ float clipc(float a) { return fminf(fmaxf(a, -FCAP), FCAP); }

static __device__ __forceinline__ bf16x8 mkfrag(const float* __restrict__ p) {
  f32x4 a = *(const f32x4*)p, b = *(const f32x4*)(p + 4);
  u32x4 wv = {pk2(a[0], a[1]), pk2(a[2], a[3]), pk2(b[0], b[1]), pk2(b[2], b[3])};
  return __builtin_bit_cast(bf16x8, wv);
}

#define MFMA16(A, B, C) __builtin_amdgcn_mfma_f32_16x16x32_bf16(A, B, C, 0, 0, 0)

static __device__ __forceinline__ f32x4 lrelu4(f32x4 v) {
  return __builtin_elementwise_max(v, v * 0.01f);
}

// 16x16x32 bf16 layouts (HW-verified rounds 3/5):
//   A: row = lane&15, k = 32*kt + 8*(lane>>4) + e
//   B: col = lane&15, k = 32*kt + 8*(lane>>4) + e
//   C: col = lane&15, row = 4*(lane>>4) + reg
// h-buffer: buf[c][kpair] @ stride 68 words (kpair = row/2, u32 = bf16x2).
//
// Producer/consumer pipeline, 1 WG/CU, 8 waves, 2 particle sets (X=0,Y=1):
//   G1 (wv 0-3): L1,L2 (owns W1,W2 rows 32wv..+31)
//   G2 (wv 4-7): L3 (rows 32(wv-4)..+31), L4+Euler (wv4 only)
// 4 slots/iter advance both sets 1 step; every LDS handoff crosses >=1
// barrier; barrier counts per wave: 1 init + 2 prologue + 63*4 = 255 (both
// branches). y state ping-pongs through LDS.
__global__ __launch_bounds__(512, 2) void ode_kernel(
    const float* __restrict__ ts, const float* __restrict__ y0,
    const float* __restrict__ W1, const float* __restrict__ b1,
    const float* __restrict__ W2, const float* __restrict__ b2,
    const float* __restrict__ W3, const float* __restrict__ b3,
    const float* __restrict__ W4, const float* __restrict__ b4,
    float* __restrict__ out) {
  const int tid = threadIdx.x;
  const int wv = __builtin_amdgcn_readfirstlane(tid >> 6);  // wave 0..7
  const int l = tid & 63;
  const int g = l >> 4;   // lane group 0..3
  const int c = l & 15;   // particle col / A-row-local
  const int gp0 = blockIdx.x * 32;

  __shared__ alignas(16) u32 hb1[2][16 * 68];
  __shared__ alignas(16) u32 hb2[2][16 * 68];
  __shared__ alignas(16) u32 hb3[2][16 * 68];
  __shared__ float yb[2][16][2];

  const int rbase = 68 * c + 4 * g;
  const f32x4 zero4 = {0.f, 0.f, 0.f, 0.f};

  // ---- init: y state + t0 output (wv0 -> set X, wv4 -> set Y) ----
  if ((wv == 0 || wv == 4) && g == 0) {
    const int set = wv >> 2;
    const float2 yv = *(const float2*)(y0 + (gp0 + 16 * set + c) * 2);
    *(__shared__ float2*)&yb[set][c][0] = yv;
    float2 st = {clipc(yv.x), clipc(yv.y)};
    *(float2*)(out + (gp0 + 16 * set + c) * 2) = st;
  }

  if (wv < 4) {
    // ================= G1: layers 1,2 =================
    bf16x8 aW1[2], aW2[2][4];
    f32x4 cb2[2];
#pragma unroll
    for (int mt = 0; mt < 2; ++mt) {
      const int R = 32 * wv + 16 * mt + c;
#pragma unroll
      for (int kt = 0; kt < 4; ++kt)
        aW2[mt][kt] = mkfrag(W2 + R * 128 + 32 * kt + 8 * g);
      u32x4 f = {0, 0, 0, 0};
      if (g == 0) {
        f[0] = pk2(W1[2 * R], W1[2 * R + 1]);
        f[1] = pk2(b1[R], 0.f);
      }
      aW1[mt] = __builtin_bit_cast(bf16x8, f);
#pragma unroll
      for (int r = 0; r < 4; ++r)
        cb2[mt][r] = b2[32 * wv + 16 * mt + 4 * g + r];
    }
    const int wbase = 68 * c + 16 * wv + 2 * g;

    auto UNIT_L1 = [&](int set) {
      const float2 yv = *(__shared__ float2*)&yb[set][c][0];
      u32x4 byw = {0, 0, 0, 0};
      if (g == 0) {
        byw[0] = pk2(yv.x, yv.y);
        byw[1] = 0x3f80u;  // bf16(1.0): bias row
      }
      const bf16x8 By = __builtin_bit_cast(bf16x8, byw);
      f32x4 C0 = lrelu4(MFMA16(aW1[0], By, zero4));
      f32x4 C1 = lrelu4(MFMA16(aW1[1], By, zero4));
      *(__shared__ u32x2*)&hb1[set][wbase]     = (u32x2){pk2(C0[0], C0[1]), pk2(C0[2], C0[3])};
      *(__shared__ u32x2*)&hb1[set][wbase + 8] = (u32x2){pk2(C1[0], C1[1]), pk2(C1[2], C1[3])};
    };
    auto UNIT_L2 = [&](int set) {
      const bf16x8 q0 = __builtin_bit_cast(bf16x8, *(const __shared__ u32x4*)&hb1[set][rbase]);
      const bf16x8 q1 = __builtin_bit_cast(bf16x8, *(const __shared__ u32x4*)&hb1[set][rbase + 16]);
      const bf16x8 q2 = __builtin_bit_cast(bf16x8, *(const __shared__ u32x4*)&hb1[set][rbase + 32]);
      const bf16x8 q3 = __builtin_bit_cast(bf16x8, *(const __shared__ u32x4*)&hb1[set][rbase + 48]);
      f32x4 D0 = MFMA16(aW2[0][0], q0, cb2[0]);
      f32x4 D1 = MFMA16(aW2[1][0], q0, cb2[1]);
      f32x4 E0 = MFMA16(aW2[0][1], q1, zero4);
      f32x4 E1 = MFMA16(aW2[1][1], q1, zero4);
      D0 = MFMA16(aW2[0][2], q2, D0);
      D1 = MFMA16(aW2[1][2], q2, D1);
      E0 = MFMA16(aW2[0][3], q3, E0);
      E1 = MFMA16(aW2[1][3], q3, E1);
      const f32x4 C0 = lrelu4(D0 + E0);
      const f32x4 C1 = lrelu4(D1 + E1);
      *(__shared__ u32x2*)&hb2[set][wbase]     = (u32x2){pk2(C0[0], C0[1]), pk2(C0[2], C0[3])};
      *(__shared__ u32x2*)&hb2[set][wbase + 8] = (u32x2){pk2(C1[0], C1[1]), pk2(C1[2], C1[3])};
    };

    __syncthreads();  // init
    UNIT_L1(0);
    __syncthreads();  // p0
    UNIT_L2(0);
    __syncthreads();  // p1
#pragma unroll 1
    for (int t = 0; t < NT - 1; ++t) {
      UNIT_L1(1);      // slot A: Y.L1(t)
      __syncthreads();
      UNIT_L2(1);      // slot B: Y.L2(t)
      __syncthreads();
      if (t < NT - 2) UNIT_L1(0);  // slot C: X.L1(t+1)
      __syncthreads();
      if (t < NT - 2) UNIT_L2(0);  // slot D: X.L2(t+1)
      __syncthreads();
    }
  } else {
    // ================= G2: layer 3 + layer 4/Euler =================
    const int s = wv - 4;
    bf16x8 aW3[2][4], aW4[4];
    f32x4 cb3[2];
#pragma unroll
    for (int mt = 0; mt < 2; ++mt) {
      const int R = 32 * s + 16 * mt + c;
#pragma unroll
      for (int kt = 0; kt < 4; ++kt)
        aW3[mt][kt] = mkfrag(W3 + R * 128 + 32 * kt + 8 * g);
#pragma unroll
      for (int r = 0; r < 4; ++r)
        cb3[mt][r] = b3[32 * s + 16 * mt + 4 * g + r];
    }
#pragma unroll
    for (int kt = 0; kt < 4; ++kt) {
      u32x4 f = {0, 0, 0, 0};
      if (c < 2) {
        const float* p = W4 + c * 128 + 32 * kt + 8 * g;
        f32x4 a = *(const f32x4*)p, b = *(const f32x4*)(p + 4);
        f = (u32x4){pk2(a[0], a[1]), pk2(a[2], a[3]), pk2(b[0], b[1]), pk2(b[2], b[3])};
      }
      aW4[kt] = __builtin_bit_cast(bf16x8, f);
    }
    const float b40 = b4[0], b41 = b4[1];
    const int wbase3 = 68 * c + 16 * s + 2 * g;

    auto UNIT_L3 = [&](int set) {
      const bf16x8 q0 = __builtin_bit_cast(bf16x8, *(const __shared__ u32x4*)&hb2[set][rbase]);
      const bf16x8 q1 = __builtin_bit_cast(bf16x8, *(const __shared__ u32x4*)&hb2[set][rbase + 16]);
      const bf16x8 q2 = __builtin_bit_cast(bf16x8, *(const __shared__ u32x4*)&hb2[set][rbase + 32]);
      const bf16x8 q3 = __builtin_bit_cast(bf16x8, *(const __shared__ u32x4*)&hb2[set][rbase + 48]);
      f32x4 D0 = MFMA16(aW3[0][0], q0, cb3[0]);
      f32x4 D1 = MFMA16(aW3[1][0], q0, cb3[1]);
      f32x4 E0 = MFMA16(aW3[0][1], q1, zero4);
      f32x4 E1 = MFMA16(aW3[1][1], q1, zero4);
      D0 = MFMA16(aW3[0][2], q2, D0);
      D1 = MFMA16(aW3[1][2], q2, D1);
      E0 = MFMA16(aW3[0][3], q3, E0);
      E1 = MFMA16(aW3[1][3], q3, E1);
      const f32x4 C0 = lrelu4(D0 + E0);
      const f32x4 C1 = lrelu4(D1 + E1);
      *(__shared__ u32x2*)&hb3[set][wbase3]     = (u32x2){pk2(C0[0], C0[1]), pk2(C0[2], C0[3])};
      *(__shared__ u32x2*)&hb3[set][wbase3 + 8] = (u32x2){pk2(C1[0], C1[1]), pk2(C1[2], C1[3])};
    };
    auto UNIT_L4E = [&](int set, float dt, int t) {
      if (wv == 4) {
        const bf16x8 q0 = __builtin_bit_cast(bf16x8, *(const __shared__ u32x4*)&hb3[set][rbase]);
        const bf16x8 q1 = __builtin_bit_cast(bf16x8, *(const __shared__ u32x4*)&hb3[set][rbase + 16]);
        const bf16x8 q2 = __builtin_bit_cast(bf16x8, *(const __shared__ u32x4*)&hb3[set][rbase + 32]);
        const bf16x8 q3 = __builtin_bit_cast(bf16x8, *(const __shared__ u32x4*)&hb3[set][rbase + 48]);
        f32x4 D = MFMA16(aW4[0], q0, zero4);
        f32x4 E = MFMA16(aW4[1], q1, zero4);
        D = MFMA16(aW4[2], q2, D);
        E = MFMA16(aW4[3], q3, E);
        const f32x4 C4 = D + E;
        if (g == 0) {
          const float2 yo = *(__shared__ float2*)&yb[set][c][0];
          const float f0 = C4[0] + b40, f1 = C4[1] + b41;
          const float y1n = yo.x + dt * (f0 - yo.x);
          const float y2n = yo.y + dt * (f1 - yo.y);
          *(__shared__ float2*)&yb[set][c][0] = (float2){y1n, y2n};
          float2 st = {clipc(y1n), clipc(y2n)};
          *(float2*)(out + (t + 1) * (NB * 2) + (gp0 + 16 * set + c) * 2) = st;
        }
      }
    };

    __syncthreads();  // init
    __syncthreads();  // p0 (match G1)
    __syncthreads();  // p1 (match G1)
#pragma unroll 1
    for (int t = 0; t < NT - 1; ++t) {
      const float dt = ts[t + 1] - ts[t];
      UNIT_L3(0);          // slot A: X.L3(t)
      __syncthreads();
      UNIT_L4E(0, dt, t);  // slot B: X.L4E(t)
      __syncthreads();
      UNIT_L3(1);          // slot C: Y.L3(t)
      __syncthreads();
      UNIT_L4E(1, dt, t);  // slot D: Y.L4E(t)
      __syncthreads();
    }
  }
}

extern "C" void kernel_launch(void* const* d_in, const int* in_sizes, int n_in,
                              void* d_out, int out_size, void* d_ws, size_t ws_size,
                              hipStream_t stream) {
  const float* ts = (const float*)d_in[0];
  const float* y0 = (const float*)d_in[1];
  const float* W1 = (const float*)d_in[2];
  const float* b1 = (const float*)d_in[3];
  const float* W2 = (const float*)d_in[4];
  const float* b2 = (const float*)d_in[5];
  const float* W3 = (const float*)d_in[6];
  const float* b3 = (const float*)d_in[7];
  const float* W4 = (const float*)d_in[8];
  const float* b4 = (const float*)d_in[9];

  ode_kernel<<<NB / 32, 512, 0, stream>>>(ts, y0, W1, b1, W2, b2, W3, b3, W4, b4,
                                          (float*)d_out);
}